// Round 4
// baseline (276.079 us; speedup 1.0000x reference)
//
#include <hip/hip_runtime.h>

// GuidedFilterND: I (8,4,768,768) f32 guide, p (8,1,768,768) f32 input, r=8, eps=1e-4.
// Stage A: box-filter 19 product channels, per-pixel 4x4 SPD solve -> (As,b) float2 + sumI (ws)
// Stage B: box-filter (As,b); q = (f(As)*sumI + f(b)) / N
// Round 4: stage A SHA 16 (grid occupancy) + 1-deep row prefetch;
//          stage B burst-loads stripe into registers (MLP) then register-rolling sums.

#define HH 768
#define WW 768
#define CC 4
#define BB 8
#define RR 8
#define EPSF 1.0e-4f

#define TA 128      // threads per block
#define OUTA 112    // output columns per block (TA - 2*RR)
#define SHA 16      // stage A rows per stripe
#define NSTRIPE (HH / SHA)    // 48
#define NBAND 7               // ceil(768/112)

#define SHB 24      // stage B rows per stripe
#define NSTRIPEB (HH / SHB)   // 32

__device__ __forceinline__ void load5(const float* __restrict__ Ib,
                                      const float* __restrict__ pb,
                                      int row, int gc, float o[5]) {
  const int off = row * WW + gc;
  const int chs = HH * WW;
  o[0] = Ib[off];
  o[1] = Ib[chs + off];
  o[2] = Ib[2 * chs + off];
  o[3] = Ib[3 * chs + off];
  o[4] = pb[off];
}

__device__ __forceinline__ void prod19(const float o[5], float pr[19]) {
  pr[0] = o[0]; pr[1] = o[1]; pr[2] = o[2]; pr[3] = o[3];
  pr[4] = o[4];
  pr[5] = o[4] * o[0]; pr[6] = o[4] * o[1]; pr[7] = o[4] * o[2]; pr[8] = o[4] * o[3];
  pr[9]  = o[0] * o[0]; pr[10] = o[0] * o[1]; pr[11] = o[0] * o[2]; pr[12] = o[0] * o[3];
  pr[13] = o[1] * o[1]; pr[14] = o[1] * o[2]; pr[15] = o[1] * o[3];
  pr[16] = o[2] * o[2]; pr[17] = o[2] * o[3];
  pr[18] = o[3] * o[3];
}

__global__ __launch_bounds__(TA) void gf_stageA(const float* __restrict__ I,
                                                const float* __restrict__ p,
                                                float2* __restrict__ AB,
                                                float* __restrict__ sumI_ws,
                                                int storeSum) {
  // thread-major, padded to 20 floats (80 B): b128 accesses, conflict-free
  __shared__ float v[TA][20];
  __shared__ float s4[TA][20];
  const int tid = threadIdx.x;
  const int band0 = (int)blockIdx.x * OUTA;
  const int r0 = (int)blockIdx.y * SHA;
  const int batch = (int)blockIdx.z;
  const int gc = band0 - RR + tid;            // column this thread's vertical sum covers
  const bool colok = (gc >= 0 && gc < WW);

  const float* Ib = I + (size_t)batch * CC * HH * WW;
  const float* pb = p + (size_t)batch * HH * WW;
  float* sIb = sumI_ws + (size_t)batch * HH * WW;

  float s[20];
#pragma unroll
  for (int k = 0; k < 20; ++k) s[k] = 0.0f;

  // warm-up: preload window of row (r0-1) = rows [r0-RR-1, r0+RR-1] clipped.
  if (colok) {
    int rlo = r0 - RR - 1; if (rlo < 0) rlo = 0;
    for (int row = rlo; row < r0 + RR; ++row) {
      float o[5]; load5(Ib, pb, row, gc, o);
      float pr[19]; prod19(o, pr);
#pragma unroll
      for (int k = 0; k < 19; ++k) s[k] += pr[k];
      if (storeSum && r0 == 0)
        sIb[row * WW + gc] = o[0] + o[1] + o[2] + o[3];
    }
  }

  // prefetch state: raw values of the add-row (r+RR) and sub-row (r-RR-1)
  float ca[5] = {0,0,0,0,0}, cb[5] = {0,0,0,0,0};
  if (colok) {
    load5(Ib, pb, r0 + RR, gc, ca);           // r0+RR <= 760, always valid
    if (r0 - RR - 1 >= 0) load5(Ib, pb, r0 - RR - 1, gc, cb);
  }

  const int oc = band0 + tid;                 // output column for threads < OUTA
  const bool outok = (tid < OUTA) && (oc < WW);
  const int nw = min(oc + RR, WW - 1) - max(oc - RR, 0) + 1;

  for (int r = r0; r < r0 + SHA; ++r) {
    float na[5] = {0,0,0,0,0}, nb[5] = {0,0,0,0,0};
    if (colok) {
      // consume prefetched rows (zero-filled when out of range -> unguarded)
      float pra[19], prb[19];
      prod19(ca, pra);
      prod19(cb, prb);
#pragma unroll
      for (int k = 0; k < 19; ++k) s[k] += pra[k] - prb[k];
      if (storeSum && (r + RR < HH))
        sIb[(r + RR) * WW + gc] = ca[0] + ca[1] + ca[2] + ca[3];
      // issue next row's loads; they stay in flight through the LDS phase
      if (r + RR + 1 < HH) load5(Ib, pb, r + RR + 1, gc, na);
      if (r - RR >= 0)     load5(Ib, pb, r - RR, gc, nb);
    }
    // publish vertical sums: 5 x b128 writes
    {
      float4* vp = (float4*)(&v[tid][0]);
      vp[0] = make_float4(s[0],  s[1],  s[2],  s[3]);
      vp[1] = make_float4(s[4],  s[5],  s[6],  s[7]);
      vp[2] = make_float4(s[8],  s[9],  s[10], s[11]);
      vp[3] = make_float4(s[12], s[13], s[14], s[15]);
      vp[4] = make_float4(s[16], s[17], s[18], 0.0f);
    }
    __syncthreads();
    float t4[20];
    if (tid < TA - 3) {
      const float* a1 = &v[tid + 1][0];
      const float* a2 = &v[tid + 2][0];
      const float* a3 = &v[tid + 3][0];
      float4* op = (float4*)(&s4[tid][0]);
#pragma unroll
      for (int j = 0; j < 5; ++j) {
        float4 xa = ((const float4*)a1)[j];
        float4 xb = ((const float4*)a2)[j];
        float4 xc = ((const float4*)a3)[j];
        float o0 = s[4*j + 0] + xa.x + xb.x + xc.x;
        float o1 = s[4*j + 1] + xa.y + xb.y + xc.y;
        float o2 = s[4*j + 2] + xa.z + xb.z + xc.z;
        float o3 = s[4*j + 3] + xa.w + xb.w + xc.w;
        op[j] = make_float4(o0, o1, o2, o3);
        t4[4*j + 0] = o0; t4[4*j + 1] = o1; t4[4*j + 2] = o2; t4[4*j + 3] = o3;
      }
    }
    __syncthreads();
    if (outok) {
      float h[20];
      const float* q4  = &s4[tid + 4][0];
      const float* q8  = &s4[tid + 8][0];
      const float* q12 = &s4[tid + 12][0];
      const float* q16 = &v[tid + 16][0];
#pragma unroll
      for (int j = 0; j < 5; ++j) {
        float4 a4 = ((const float4*)q4)[j];
        float4 b4 = ((const float4*)q8)[j];
        float4 c4 = ((const float4*)q12)[j];
        float4 d4 = ((const float4*)q16)[j];
        h[4*j + 0] = t4[4*j + 0] + a4.x + b4.x + c4.x + d4.x;
        h[4*j + 1] = t4[4*j + 1] + a4.y + b4.y + c4.y + d4.y;
        h[4*j + 2] = t4[4*j + 2] + a4.z + b4.z + c4.z + d4.z;
        h[4*j + 3] = t4[4*j + 3] + a4.w + b4.w + c4.w + d4.w;
      }
      const int nh = min(r + RR, HH - 1) - max(r - RR, 0) + 1;
      const float invN = 1.0f / (float)(nh * nw);
      float Im0 = h[0] * invN, Im1 = h[1] * invN, Im2 = h[2] * invN, Im3 = h[3] * invN;
      float pm = h[4] * invN;
      float ft0 = h[5] * invN - pm * Im0;
      float ft1 = h[6] * invN - pm * Im1;
      float ft2 = h[7] * invN - pm * Im2;
      float ft3 = h[8] * invN - pm * Im3;
      float m[4][4];
      m[0][0] = h[9]  * invN + EPSF;
      m[0][1] = h[10] * invN;
      m[0][2] = h[11] * invN;
      m[0][3] = h[12] * invN;
      m[1][1] = h[13] * invN + EPSF;
      m[1][2] = h[14] * invN;
      m[1][3] = h[15] * invN;
      m[2][2] = h[16] * invN + EPSF;
      m[2][3] = h[17] * invN;
      m[3][3] = h[18] * invN + EPSF;
      m[1][0] = m[0][1]; m[2][0] = m[0][2]; m[3][0] = m[0][3];
      m[2][1] = m[1][2]; m[3][1] = m[1][3]; m[3][2] = m[2][3];
      float y[4] = {1.0f, 1.0f, 1.0f, 1.0f};
#pragma unroll
      for (int k = 0; k < 4; ++k) {
        float piv = 1.0f / m[k][k];
#pragma unroll
        for (int j = 0; j < 4; ++j) m[k][j] *= piv;
        y[k] *= piv;
#pragma unroll
        for (int i = 0; i < 4; ++i) {
          if (i == k) continue;
          float f = m[i][k];
#pragma unroll
          for (int j = 0; j < 4; ++j) m[i][j] -= f * m[k][j];
          y[i] -= f * y[k];
        }
      }
      float Asum = ft0 * y[0] + ft1 * y[1] + ft2 * y[2] + ft3 * y[3];
      float bv = pm - Asum * (Im0 + Im1 + Im2 + Im3);
      AB[((size_t)batch * HH + r) * WW + oc] = make_float2(Asum, bv);
    }
    __syncthreads();
#pragma unroll
    for (int k = 0; k < 5; ++k) { ca[k] = na[k]; cb[k] = nb[k]; }
  }
}

__global__ __launch_bounds__(TA) void gf_stageB(const float* __restrict__ I,
                                                const float2* __restrict__ AB,
                                                const float* __restrict__ sumI_ws,
                                                float* __restrict__ q, int useSum) {
  __shared__ float2 v2[TA];
  __shared__ float2 s42[TA];
  const int tid = threadIdx.x;
  const int band0 = (int)blockIdx.x * OUTA;
  const int r0 = (int)blockIdx.y * SHB;
  const int batch = (int)blockIdx.z;
  const int gc = band0 - RR + tid;
  const bool colok = (gc >= 0 && gc < WW);

  const float2* ABb = AB + (size_t)batch * HH * WW;
  const float* sIb = sumI_ws + (size_t)batch * HH * WW;
  const float* Ib = I + (size_t)batch * CC * HH * WW;

  const int oc = band0 + tid;
  const bool outok = (tid < OUTA) && (oc < WW);
  const int nw = min(oc + RR, WW - 1) - max(oc - RR, 0) + 1;

  // burst-load the whole stripe's AB window: SHB+17 independent loads (MLP)
  float2 w[SHB + 17];
#pragma unroll
  for (int k = 0; k < SHB + 17; ++k) {
    const int row = r0 - RR - 1 + k;
    const bool ok = colok && (row >= 0) && (row < HH);
    w[k] = ok ? ABb[row * WW + gc] : make_float2(0.0f, 0.0f);
  }
  // burst-load sumI for the stripe's output pixels
  float sm[SHB];
  if (useSum) {
#pragma unroll
    for (int j = 0; j < SHB; ++j)
      sm[j] = outok ? sIb[(r0 + j) * WW + oc] : 0.0f;
  }

  // S = window of row (r0-1) = w[0..16]
  float sA = 0.0f, sB = 0.0f;
#pragma unroll
  for (int k = 0; k < 17; ++k) { sA += w[k].x; sB += w[k].y; }

#pragma unroll
  for (int j = 0; j < SHB; ++j) {
    const int r = r0 + j;
    sA += w[j + 17].x - w[j].x;
    sB += w[j + 17].y - w[j].y;
    v2[tid] = make_float2(sA, sB);
    __syncthreads();
    float tx = 0.0f, ty = 0.0f;
    if (tid < TA - 3) {
      float2 a = v2[tid + 1], b = v2[tid + 2], c = v2[tid + 3];
      tx = sA + a.x + b.x + c.x;
      ty = sB + a.y + b.y + c.y;
      s42[tid] = make_float2(tx, ty);
    }
    __syncthreads();
    if (outok) {
      float2 a = s42[tid + 4], b = s42[tid + 8], c = s42[tid + 12], d = v2[tid + 16];
      float hA = tx + a.x + b.x + c.x + d.x;
      float hB = ty + a.y + b.y + c.y + d.y;
      const int nh = min(r + RR, HH - 1) - max(r - RR, 0) + 1;
      const float invN = 1.0f / (float)(nh * nw);
      float sumI;
      if (useSum) {
        sumI = sm[j];
      } else {
        const int off = r * WW + oc;
        const int chs = HH * WW;
        sumI = Ib[off] + Ib[chs + off] + Ib[2 * chs + off] + Ib[3 * chs + off];
      }
      q[((size_t)batch * HH + r) * WW + oc] = (hA * sumI + hB) * invN;
    }
    __syncthreads();
  }
}

extern "C" void kernel_launch(void* const* d_in, const int* in_sizes, int n_in,
                              void* d_out, int out_size, void* d_ws, size_t ws_size,
                              hipStream_t stream) {
  const float* I = (const float*)d_in[0];   // (8,4,768,768) f32
  const float* p = (const float*)d_in[1];   // (8,1,768,768) f32
  float* q = (float*)d_out;                 // (8,1,768,768) f32

  const size_t npix = (size_t)BB * HH * WW;
  float2* AB = (float2*)d_ws;                               // 37.75 MB
  float* sumI_ws = (float*)(AB + npix);                     // +18.87 MB
  const size_t need = npix * sizeof(float2) + npix * sizeof(float);
  const int useSum = (ws_size >= need) ? 1 : 0;             // constant across calls

  dim3 gridA(NBAND, NSTRIPE, BB);
  dim3 gridB(NBAND, NSTRIPEB, BB);
  dim3 block(TA);
  hipLaunchKernelGGL(gf_stageA, gridA, block, 0, stream, I, p, AB, sumI_ws, useSum);
  hipLaunchKernelGGL(gf_stageB, gridB, block, 0, stream, I, AB, sumI_ws, q, useSum);
}

// Round 5
// 224.067 us; speedup vs baseline: 1.2321x; 1.2321x over previous
//
#include <hip/hip_runtime.h>

// GuidedFilterND: I (8,4,768,768) f32 guide, p (8,1,768,768) f32 input, r=8, eps=1e-4.
// Stage A: box-filter 19 product channels, per-pixel 4x4 SPD solve -> (As,b) float2 + sumI (ws)
// Stage B: box-filter (As,b); q = (f(As)*sumI + f(b)) / N
// Round 5: stage A reverted to round-3 exact form (SHA=24, no prefetch — round 4's
//          prefetch restructure induced 3.8e7 LDS bank conflicts via compiler
//          re-splitting the b128 accesses). Stage B: register burst-load, SHB=16.

#define HH 768
#define WW 768
#define CC 4
#define BB 8
#define RR 8
#define EPSF 1.0e-4f

#define TA 128      // threads per block
#define OUTA 112    // output columns per block (TA - 2*RR)
#define SHA 24      // stage A rows per stripe (round-3 proven)
#define NSTRIPE (HH / SHA)    // 32
#define NBAND 7               // ceil(768/112)

#define SHB 16      // stage B rows per stripe
#define NSTRIPEB (HH / SHB)   // 48

__device__ __forceinline__ void loadpix(const float* __restrict__ Ib,
                                        const float* __restrict__ pb,
                                        int row, int gc, float pr[19]) {
  const int off = row * WW + gc;
  const int chs = HH * WW;
  float i0 = Ib[off];
  float i1 = Ib[chs + off];
  float i2 = Ib[2 * chs + off];
  float i3 = Ib[3 * chs + off];
  float pv = pb[off];
  pr[0] = i0; pr[1] = i1; pr[2] = i2; pr[3] = i3;
  pr[4] = pv;
  pr[5] = pv * i0; pr[6] = pv * i1; pr[7] = pv * i2; pr[8] = pv * i3;
  pr[9]  = i0 * i0; pr[10] = i0 * i1; pr[11] = i0 * i2; pr[12] = i0 * i3;
  pr[13] = i1 * i1; pr[14] = i1 * i2; pr[15] = i1 * i3;
  pr[16] = i2 * i2; pr[17] = i2 * i3;
  pr[18] = i3 * i3;
}

__global__ __launch_bounds__(TA) void gf_stageA(const float* __restrict__ I,
                                                const float* __restrict__ p,
                                                float2* __restrict__ AB,
                                                float* __restrict__ sumI_ws,
                                                int storeSum) {
  // thread-major, padded to 20 floats (80 B): b128 accesses, conflict-free
  __shared__ float v[TA][20];
  __shared__ float s4[TA][20];
  const int tid = threadIdx.x;
  const int band0 = (int)blockIdx.x * OUTA;
  const int r0 = (int)blockIdx.y * SHA;
  const int batch = (int)blockIdx.z;
  const int gc = band0 - RR + tid;            // column this thread's vertical sum covers
  const bool colok = (gc >= 0 && gc < WW);

  const float* Ib = I + (size_t)batch * CC * HH * WW;
  const float* pb = p + (size_t)batch * HH * WW;
  float* sIb = sumI_ws + (size_t)batch * HH * WW;

  float s[20];
#pragma unroll
  for (int k = 0; k < 20; ++k) s[k] = 0.0f;

  // warm-up: preload window of row (r0-1) = rows [r0-RR-1, r0+RR-1] clipped.
  if (colok) {
    int rlo = r0 - RR - 1; if (rlo < 0) rlo = 0;
    for (int row = rlo; row < r0 + RR; ++row) {
      float pr[19]; loadpix(Ib, pb, row, gc, pr);
#pragma unroll
      for (int k = 0; k < 19; ++k) s[k] += pr[k];
      // rows 0..7 are only ever touched by stripe 0's warm-up: store sumI here
      if (storeSum && r0 == 0)
        sIb[row * WW + gc] = pr[0] + pr[1] + pr[2] + pr[3];
    }
  }

  const int oc = band0 + tid;                 // output column for threads < OUTA
  const bool outok = (tid < OUTA) && (oc < WW);
  const int nw = min(oc + RR, WW - 1) - max(oc - RR, 0) + 1;

  for (int r = r0; r < r0 + SHA; ++r) {
    if (colok) {
      int rl = r + RR;
      if (rl < HH) {
        float pr[19]; loadpix(Ib, pb, rl, gc, pr);
#pragma unroll
        for (int k = 0; k < 19; ++k) s[k] += pr[k];
        if (storeSum)
          sIb[rl * WW + gc] = pr[0] + pr[1] + pr[2] + pr[3];
      }
      int rt = r - RR - 1;
      if (rt >= 0) {
        float pr[19]; loadpix(Ib, pb, rt, gc, pr);
#pragma unroll
        for (int k = 0; k < 19; ++k) s[k] -= pr[k];
      }
    }
    // publish vertical sums: 5 x b128 writes
    {
      float4* vp = (float4*)(&v[tid][0]);
      vp[0] = make_float4(s[0],  s[1],  s[2],  s[3]);
      vp[1] = make_float4(s[4],  s[5],  s[6],  s[7]);
      vp[2] = make_float4(s[8],  s[9],  s[10], s[11]);
      vp[3] = make_float4(s[12], s[13], s[14], s[15]);
      vp[4] = make_float4(s[16], s[17], s[18], 0.0f);
    }
    __syncthreads();
    float t4[20];
    if (tid < TA - 3) {
      const float* a1 = &v[tid + 1][0];
      const float* a2 = &v[tid + 2][0];
      const float* a3 = &v[tid + 3][0];
      float4* op = (float4*)(&s4[tid][0]);
#pragma unroll
      for (int j = 0; j < 5; ++j) {
        float4 xa = ((const float4*)a1)[j];
        float4 xb = ((const float4*)a2)[j];
        float4 xc = ((const float4*)a3)[j];
        float o0 = s[4*j + 0] + xa.x + xb.x + xc.x;
        float o1 = s[4*j + 1] + xa.y + xb.y + xc.y;
        float o2 = s[4*j + 2] + xa.z + xb.z + xc.z;
        float o3 = s[4*j + 3] + xa.w + xb.w + xc.w;
        op[j] = make_float4(o0, o1, o2, o3);
        t4[4*j + 0] = o0; t4[4*j + 1] = o1; t4[4*j + 2] = o2; t4[4*j + 3] = o3;
      }
    }
    __syncthreads();
    if (outok) {
      float h[20];
      const float* q4  = &s4[tid + 4][0];
      const float* q8  = &s4[tid + 8][0];
      const float* q12 = &s4[tid + 12][0];
      const float* q16 = &v[tid + 16][0];
#pragma unroll
      for (int j = 0; j < 5; ++j) {
        float4 a4 = ((const float4*)q4)[j];
        float4 b4 = ((const float4*)q8)[j];
        float4 c4 = ((const float4*)q12)[j];
        float4 d4 = ((const float4*)q16)[j];
        h[4*j + 0] = t4[4*j + 0] + a4.x + b4.x + c4.x + d4.x;
        h[4*j + 1] = t4[4*j + 1] + a4.y + b4.y + c4.y + d4.y;
        h[4*j + 2] = t4[4*j + 2] + a4.z + b4.z + c4.z + d4.z;
        h[4*j + 3] = t4[4*j + 3] + a4.w + b4.w + c4.w + d4.w;
      }
      const int nh = min(r + RR, HH - 1) - max(r - RR, 0) + 1;
      const float invN = 1.0f / (float)(nh * nw);
      float Im0 = h[0] * invN, Im1 = h[1] * invN, Im2 = h[2] * invN, Im3 = h[3] * invN;
      float pm = h[4] * invN;
      float ft0 = h[5] * invN - pm * Im0;
      float ft1 = h[6] * invN - pm * Im1;
      float ft2 = h[7] * invN - pm * Im2;
      float ft3 = h[8] * invN - pm * Im3;
      float m[4][4];
      m[0][0] = h[9]  * invN + EPSF;
      m[0][1] = h[10] * invN;
      m[0][2] = h[11] * invN;
      m[0][3] = h[12] * invN;
      m[1][1] = h[13] * invN + EPSF;
      m[1][2] = h[14] * invN;
      m[1][3] = h[15] * invN;
      m[2][2] = h[16] * invN + EPSF;
      m[2][3] = h[17] * invN;
      m[3][3] = h[18] * invN + EPSF;
      m[1][0] = m[0][1]; m[2][0] = m[0][2]; m[3][0] = m[0][3];
      m[2][1] = m[1][2]; m[3][1] = m[1][3]; m[3][2] = m[2][3];
      float y[4] = {1.0f, 1.0f, 1.0f, 1.0f};
#pragma unroll
      for (int k = 0; k < 4; ++k) {
        float piv = 1.0f / m[k][k];
#pragma unroll
        for (int j = 0; j < 4; ++j) m[k][j] *= piv;
        y[k] *= piv;
#pragma unroll
        for (int i = 0; i < 4; ++i) {
          if (i == k) continue;
          float f = m[i][k];
#pragma unroll
          for (int j = 0; j < 4; ++j) m[i][j] -= f * m[k][j];
          y[i] -= f * y[k];
        }
      }
      float Asum = ft0 * y[0] + ft1 * y[1] + ft2 * y[2] + ft3 * y[3];
      float bv = pm - Asum * (Im0 + Im1 + Im2 + Im3);
      AB[((size_t)batch * HH + r) * WW + oc] = make_float2(Asum, bv);
    }
    __syncthreads();
  }
}

__global__ __launch_bounds__(TA) void gf_stageB(const float* __restrict__ I,
                                                const float2* __restrict__ AB,
                                                const float* __restrict__ sumI_ws,
                                                float* __restrict__ q, int useSum) {
  __shared__ float2 v2[TA];
  __shared__ float2 s42[TA];
  const int tid = threadIdx.x;
  const int band0 = (int)blockIdx.x * OUTA;
  const int r0 = (int)blockIdx.y * SHB;
  const int batch = (int)blockIdx.z;
  const int gc = band0 - RR + tid;
  const bool colok = (gc >= 0 && gc < WW);

  const float2* ABb = AB + (size_t)batch * HH * WW;
  const float* sIb = sumI_ws + (size_t)batch * HH * WW;
  const float* Ib = I + (size_t)batch * CC * HH * WW;

  const int oc = band0 + tid;
  const bool outok = (tid < OUTA) && (oc < WW);
  const int nw = min(oc + RR, WW - 1) - max(oc - RR, 0) + 1;

  // burst-load the whole stripe's AB window: SHB+17 = 33 independent loads (MLP)
  float2 w[SHB + 17];
#pragma unroll
  for (int k = 0; k < SHB + 17; ++k) {
    const int row = r0 - RR - 1 + k;
    const bool ok = colok && (row >= 0) && (row < HH);
    w[k] = ok ? ABb[row * WW + gc] : make_float2(0.0f, 0.0f);
  }
  // burst-load sumI for the stripe's output pixels
  float sm[SHB];
  if (useSum) {
#pragma unroll
    for (int j = 0; j < SHB; ++j)
      sm[j] = outok ? sIb[(r0 + j) * WW + oc] : 0.0f;
  }

  // S = window of row (r0-1) = w[0..16]
  float sA = 0.0f, sB = 0.0f;
#pragma unroll
  for (int k = 0; k < 17; ++k) { sA += w[k].x; sB += w[k].y; }

#pragma unroll
  for (int j = 0; j < SHB; ++j) {
    const int r = r0 + j;
    sA += w[j + 17].x - w[j].x;
    sB += w[j + 17].y - w[j].y;
    v2[tid] = make_float2(sA, sB);
    __syncthreads();
    float tx = 0.0f, ty = 0.0f;
    if (tid < TA - 3) {
      float2 a = v2[tid + 1], b = v2[tid + 2], c = v2[tid + 3];
      tx = sA + a.x + b.x + c.x;
      ty = sB + a.y + b.y + c.y;
      s42[tid] = make_float2(tx, ty);
    }
    __syncthreads();
    if (outok) {
      float2 a = s42[tid + 4], b = s42[tid + 8], c = s42[tid + 12], d = v2[tid + 16];
      float hA = tx + a.x + b.x + c.x + d.x;
      float hB = ty + a.y + b.y + c.y + d.y;
      const int nh = min(r + RR, HH - 1) - max(r - RR, 0) + 1;
      const float invN = 1.0f / (float)(nh * nw);
      float sumI;
      if (useSum) {
        sumI = sm[j];
      } else {
        const int off = r * WW + oc;
        const int chs = HH * WW;
        sumI = Ib[off] + Ib[chs + off] + Ib[2 * chs + off] + Ib[3 * chs + off];
      }
      q[((size_t)batch * HH + r) * WW + oc] = (hA * sumI + hB) * invN;
    }
    __syncthreads();
  }
}

extern "C" void kernel_launch(void* const* d_in, const int* in_sizes, int n_in,
                              void* d_out, int out_size, void* d_ws, size_t ws_size,
                              hipStream_t stream) {
  const float* I = (const float*)d_in[0];   // (8,4,768,768) f32
  const float* p = (const float*)d_in[1];   // (8,1,768,768) f32
  float* q = (float*)d_out;                 // (8,1,768,768) f32

  const size_t npix = (size_t)BB * HH * WW;
  float2* AB = (float2*)d_ws;                               // 37.75 MB
  float* sumI_ws = (float*)(AB + npix);                     // +18.87 MB
  const size_t need = npix * sizeof(float2) + npix * sizeof(float);
  const int useSum = (ws_size >= need) ? 1 : 0;             // constant across calls

  dim3 gridA(NBAND, NSTRIPE, BB);
  dim3 gridB(NBAND, NSTRIPEB, BB);
  dim3 block(TA);
  hipLaunchKernelGGL(gf_stageA, gridA, block, 0, stream, I, p, AB, sumI_ws, useSum);
  hipLaunchKernelGGL(gf_stageB, gridB, block, 0, stream, I, AB, sumI_ws, q, useSum);
}